// Round 10
// baseline (569.110 us; speedup 1.0000x reference)
//
#include <hip/hip_runtime.h>

typedef unsigned short u16;
typedef unsigned int u32;
typedef short s8v __attribute__((ext_vector_type(8)));
typedef float f4v __attribute__((ext_vector_type(4)));
typedef int i4v __attribute__((ext_vector_type(4)));

__device__ __forceinline__ u16 f2bf(float f) {
  u32 u = __builtin_bit_cast(u32, f);
  u32 r = (u + 0x7FFFu + ((u >> 16) & 1u)) >> 16;
  return (u16)r;
}
__device__ __forceinline__ float bf2f(u16 h) {
  u32 u = ((u32)h) << 16;
  return __builtin_bit_cast(float, u);
}
__device__ __forceinline__ int q8(float x) {
  return (int)__builtin_rintf(fmaxf(-127.f, fminf(127.f, x)));
}

// async global->LDS, 16B per lane; LDS dest is wave-uniform base + lane*16
__device__ __forceinline__ void gload16(const void* g, void* l) {
  __builtin_amdgcn_global_load_lds(
      (const __attribute__((address_space(1))) void*)g,
      (__attribute__((address_space(3))) void*)l, 16, 0, 0);
}

// ---------------- fused weight converts: Wz,Wr -> wzr ; Wh -> whb ----------------
__global__ __launch_bounds__(256) void cvt_w3(const float* __restrict__ Wz,
                                              const float* __restrict__ Wr,
                                              const float* __restrict__ Wh,
                                              u16* __restrict__ wzr,
                                              u16* __restrict__ whb) {
  int i = blockIdx.x * 256 + threadIdx.x;
  if (i >= 46080) return;
  const float* src;
  u16* dst;
  int j;
  if (i < 15360) {
    src = Wz; dst = wzr; j = i;
  } else if (i < 30720) {
    src = Wr; dst = wzr + 61440; j = i - 15360;
  } else {
    src = Wh; dst = whb; j = i - 30720;
  }
  float4 v = *reinterpret_cast<const float4*>(&src[j * 4]);
  u16 o0 = f2bf(v.x), o1 = f2bf(v.y), o2 = f2bf(v.z), o3 = f2bf(v.w);
  *reinterpret_cast<uint2*>(&dst[j * 4]) =
      make_uint2(o0 | ((u32)o1 << 16), o2 | ((u32)o3 << 16));
}

// ---------------- adj f32 -> i8 (value * 2^18; adj < 2^-12 so fits in [0,64]) ----
__global__ __launch_bounds__(256) void cvt_adj_i8(const float* __restrict__ in,
                                                  u32* __restrict__ out, int n4) {
  int i = blockIdx.x * 256 + threadIdx.x;
  if (i >= n4) return;
  float4 v = reinterpret_cast<const float4*>(in)[i];
  const float s = 262144.f;  // 2^18
  int a = (int)__builtin_rintf(v.x * s), b = (int)__builtin_rintf(v.y * s);
  int c = (int)__builtin_rintf(v.z * s), d = (int)__builtin_rintf(v.w * s);
  out[i] = (u32)(a & 255) | ((u32)(b & 255) << 8) | ((u32)(c & 255) << 16) |
           ((u32)(d & 255) << 24);
}

// ---------------- prep: xh -> grows (bf16 rows) + gt0q (i8*16, transposed) ------
__global__ __launch_bounds__(256) void prep_kernel(const float* __restrict__ x_t,
                                                   const float* __restrict__ h_prev,
                                                   char* __restrict__ gt0q,
                                                   u16* __restrict__ grows) {
  __shared__ char T8[160][80];
  const int t = threadIdx.x;
  const int n0 = blockIdx.x * 64;
  const int b = blockIdx.y;
#pragma unroll
  for (int q = 0; q < 2; ++q) {
    int idx = t + q * 256;
    int n_loc = idx >> 3, f = (idx & 7) << 2;
    int n = n0 + n_loc;
    float4 v = *reinterpret_cast<const float4*>(&x_t[((size_t)b * 4096 + n) * 32 + f]);
    u16 o[4] = {f2bf(v.x), f2bf(v.y), f2bf(v.z), f2bf(v.w)};
    *reinterpret_cast<uint2*>(&grows[((size_t)n * 16 + b) * 480 + f]) =
        make_uint2(o[0] | ((u32)o[1] << 16), o[2] | ((u32)o[3] << 16));
    T8[f + 0][n_loc] = (char)q8(v.x * 16.f);
    T8[f + 1][n_loc] = (char)q8(v.y * 16.f);
    T8[f + 2][n_loc] = (char)q8(v.z * 16.f);
    T8[f + 3][n_loc] = (char)q8(v.w * 16.f);
  }
#pragma unroll
  for (int q = 0; q < 8; ++q) {
    int idx = t + q * 256;
    int n_loc = idx >> 5, f = (idx & 31) << 2;
    int n = n0 + n_loc;
    float4 v = *reinterpret_cast<const float4*>(&h_prev[((size_t)b * 4096 + n) * 128 + f]);
    u16 o[4] = {f2bf(v.x), f2bf(v.y), f2bf(v.z), f2bf(v.w)};
    *reinterpret_cast<uint2*>(&grows[((size_t)n * 16 + b) * 480 + 32 + f]) =
        make_uint2(o[0] | ((u32)o[1] << 16), o[2] | ((u32)o[3] << 16));
    T8[32 + f + 0][n_loc] = (char)q8(v.x * 16.f);
    T8[32 + f + 1][n_loc] = (char)q8(v.y * 16.f);
    T8[32 + f + 2][n_loc] = (char)q8(v.z * 16.f);
    T8[32 + f + 3][n_loc] = (char)q8(v.w * 16.f);
  }
  __syncthreads();
  if (t < 160) {
    char* dst = &gt0q[((size_t)b * 160 + t) * 4096 + n0];
    const char* src = &T8[t][0];
#pragma unroll
    for (int q = 0; q < 4; ++q)
      reinterpret_cast<uint4*>(dst)[q] = *reinterpret_cast<const uint4*>(src + q * 16);
  }
}

// ------------- mix GEMM i8: 64x128 tile, 4 waves (32x64 each), hybrid staging --
// A (64x64/step) via global_load_lds depth-2 triple-buffer; B (128x64/step) via
// global_load->reg->ds_write double-buffer (r8-validated). Counted in-flight
// loads: the compiler's auto-wait before ds_write (vmcnt(3)) retires A(t+1);
// A/B(t+2) stay in flight across the barrier. Grid 1280/1024 -> 5 blocks/CU
// (r3 evidence: block-level co-residency is the remaining overlap lever).
// LDS chunk swizzle c ^ ((row>>1)&3): pre-swizzled global source, linear
// dest/write, swizzled read -> conflict-free.
template <int CAND, int WT>
__global__ __launch_bounds__(256) void gemm_mix_i8(const char* __restrict__ A,
                                                   const char* __restrict__ Bt,
                                                   char* __restrict__ outq,
                                                   u16* __restrict__ grows_slice,
                                                   float desc, float qdesc) {
  __shared__ char Ab[3][4096];  // A[64][64] per slot, depth-2 DMA
  __shared__ char Bb[2][8192];  // B[128][64] per slot, reg-staged dbuf
  const int tid = threadIdx.x;
  const int lane = tid & 63, wid = tid >> 6;
  const int wr = wid >> 1, wc = wid & 1;

  const int flat = blockIdx.x;
  const int xcd = flat & 7, r = flat >> 3;
  const int bx = (xcd << 3) | (r & 7), by = r >> 3;  // XCD owns 8 consecutive bx
  const int bm0 = bx * 64;
  const int bn0 = CAND ? (by * 160 + 32) : (by * 128);

  const int gchunk = (lane & 3) ^ ((lane >> 3) & 3);
  // A staging: wave wid covers rows [16wid, 16wid+16), 1 gload16
  const char* aptr = &A[(size_t)(bm0 + wid * 16 + (lane >> 2)) * 4096 + gchunk * 16];
  const int lwsA = wid * 1024;
  // B staging: wave wid covers rows [32wid, 32wid+32), 2 reg loads + 2 ds_writes
  const char* bptr = &Bt[(size_t)(bn0 + wid * 32 + (lane >> 2)) * 4096 + gchunk * 16];
  const int lwlB = wid * 2048 + lane * 16;  // row*64 + chunk*16 collapses to this

  i4v acc[2][4];
#pragma unroll
  for (int i = 0; i < 2; ++i)
#pragma unroll
    for (int j = 0; j < 4; ++j) acc[i][j] = (i4v){0, 0, 0, 0};

  const int rsel = lane & 15;
  const int rch = (lane >> 4) ^ ((rsel >> 1) & 3);   // swizzled read chunk
  const int ra0 = (wr * 32 + rsel) * 64 + rch * 16;  // A frag base (i=0)
  const int rb0 = (wc * 64 + rsel) * 64 + rch * 16;  // B frag base (j=0)

  uint4 bqE[2], bqO[2];

  auto DMA_A = [&](char* buf, int k0) { gload16(aptr + k0, buf + lwsA); };
  auto LOAD_B = [&](uint4 (&bq)[2], int k0) {
    bq[0] = *reinterpret_cast<const uint4*>(bptr + k0);
    bq[1] = *reinterpret_cast<const uint4*>(bptr + (size_t)16 * 4096 + k0);
  };
  auto WRITE_B = [&](char* slot, const uint4 (&bq)[2]) {
    *reinterpret_cast<uint4*>(slot + lwlB) = bq[0];
    *reinterpret_cast<uint4*>(slot + lwlB + 1024) = bq[1];
  };
  auto COMPUTE = [&](const char* Ac, const char* Bc) {
    i4v af[2], bfr[4];
#pragma unroll
    for (int i = 0; i < 2; ++i)
      af[i] = *reinterpret_cast<const i4v*>(Ac + ra0 + i * 1024);
#pragma unroll
    for (int j = 0; j < 4; ++j)
      bfr[j] = *reinterpret_cast<const i4v*>(Bc + rb0 + j * 1024);
#pragma unroll
    for (int i = 0; i < 2; ++i)
#pragma unroll
      for (int j = 0; j < 4; ++j)
        acc[i][j] =
            __builtin_amdgcn_mfma_i32_16x16x64_i8(af[i], bfr[j], acc[i][j], 0, 0, 0);
  };
  auto BARRIER = [&]() {
    asm volatile("s_waitcnt lgkmcnt(0)" ::: "memory");  // ds_write visible
    __builtin_amdgcn_s_barrier();
    __builtin_amdgcn_sched_barrier(0);
  };

  // prologue: A0,A1 via DMA; B0,B1 -> regs; write B0 (auto-wait retires A0,A1,B0)
  DMA_A(&Ab[0][0], 0);
  LOAD_B(bqE, 0);
  DMA_A(&Ab[1][0], 64);
  LOAD_B(bqO, 64);
  WRITE_B(&Bb[0][0], bqE);
  BARRIER();

  char *Ac = &Ab[0][0], *An = &Ab[1][0], *Af = &Ab[2][0];
  char *Bc = &Bb[0][0], *Bo = &Bb[1][0];
  for (int p = 0; p < 31; ++p) {
    const int k0 = p * 128;
    // even tile t=2p
    DMA_A(Af, k0 + 128);
    LOAD_B(bqE, k0 + 128);  // reload for t+2 (old bqE consumed by WRITE_B earlier)
    COMPUTE(Ac, Bc);
    WRITE_B(Bo, bqO);       // B(t+1); auto vmcnt wait retires A(t+1) too
    BARRIER();
    { char* t = Ac; Ac = An; An = Af; Af = t; }
    { char* t = Bc; Bc = Bo; Bo = t; }
    // odd tile t=2p+1
    DMA_A(Af, k0 + 192);
    LOAD_B(bqO, k0 + 192);
    COMPUTE(Ac, Bc);
    WRITE_B(Bo, bqE);
    BARRIER();
    { char* t = Ac; Ac = An; An = Af; Af = t; }
    { char* t = Bc; Bc = Bo; Bo = t; }
  }
  // tail: tiles 62, 63
  COMPUTE(Ac, Bc);
  WRITE_B(Bo, bqO);
  BARRIER();
  COMPUTE(An, Bo);

  const int mbase = bm0 + wr * 32 + ((lane >> 4) << 2);
  const int cbase = bn0 + wc * 64 + (lane & 15);
#pragma unroll
  for (int j = 0; j < 4; ++j) {
    int c = cbase + j * 16;
    int cb = c / 160;
    int cf = c - cb * 160;
#pragma unroll
    for (int i = 0; i < 2; ++i) {
      int m = mbase + i * 16;
      float f[4];
#pragma unroll
      for (int q = 0; q < 4; ++q) f[q] = (float)acc[i][j][q] * desc;
      if (WT) {
        int q0 = q8((float)acc[i][j][0] * qdesc), q1 = q8((float)acc[i][j][1] * qdesc);
        int q2 = q8((float)acc[i][j][2] * qdesc), q3 = q8((float)acc[i][j][3] * qdesc);
        *reinterpret_cast<u32*>(&outq[(size_t)c * 4096 + m]) =
            (u32)(q0 & 255) | ((u32)(q1 & 255) << 8) | ((u32)(q2 & 255) << 16) |
            ((u32)(q3 & 255) << 24);
      }
#pragma unroll
      for (int q = 0; q < 4; ++q)
        grows_slice[((size_t)(m + q) * 16 + cb) * 480 + cf] = f2bf(f[q]);
    }
  }
}

// ---------------- gate GEMM (bf16, 2-phase + swizzle) --------------------------
// MODE 1: z/r. c<128 -> sigmoid+bias0 -> out0 ; else sigmoid+bias1 -> out1
// MODE 2: h gate. tanh+bias0 -> out0
template <int MODE>
__global__ __launch_bounds__(256) void gemm_gate(const u16* __restrict__ A,
                                                 const u16* __restrict__ Bt,
                                                 u16* __restrict__ out0,
                                                 u16* __restrict__ out1,
                                                 const float* __restrict__ bias0,
                                                 const float* __restrict__ bias1) {
  __shared__ u16 As[2][128 * 32];
  __shared__ u16 Bs[2][128 * 32];
  const int tid = threadIdx.x;
  const int lane = tid & 63, wid = tid >> 6;
  const int wr = wid >> 1, wc = wid & 1;
  const int bm0 = blockIdx.x * 128, bn0 = blockIdx.y * 128;

  const int gchunk = (lane & 3) ^ ((lane >> 3) & 3);
  const u16* aptr = &A[(size_t)(bm0 + wid * 32 + (lane >> 2)) * 480 + gchunk * 8];
  const u16* bptr = &Bt[(size_t)(bn0 + wid * 32 + (lane >> 2)) * 480 + gchunk * 8];

  f4v acc[4][4];
#pragma unroll
  for (int i = 0; i < 4; ++i)
#pragma unroll
    for (int j = 0; j < 4; ++j) acc[i][j] = (f4v){0.f, 0.f, 0.f, 0.f};

  const int rsel = lane & 15;
  const int rch = (lane >> 4) ^ ((rsel >> 1) & 3);

#pragma unroll
  for (int q = 0; q < 2; ++q) {
    gload16(aptr + (size_t)q * 16 * 480, &As[0][wid * 1024 + q * 512]);
    gload16(bptr + (size_t)q * 16 * 480, &Bs[0][wid * 1024 + q * 512]);
  }
  __syncthreads();

  int cur = 0;
  for (int k0 = 0; k0 < 480; k0 += 32) {
    const int nxt = cur ^ 1;
    if (k0 + 32 < 480) {
#pragma unroll
      for (int q = 0; q < 2; ++q) {
        gload16(aptr + (size_t)q * 16 * 480 + (k0 + 32), &As[nxt][wid * 1024 + q * 512]);
        gload16(bptr + (size_t)q * 16 * 480 + (k0 + 32), &Bs[nxt][wid * 1024 + q * 512]);
      }
    }
    s8v af[4], bfr[4];
#pragma unroll
    for (int i = 0; i < 4; ++i) {
      af[i] = *reinterpret_cast<const s8v*>(
          &As[cur][(wr * 64 + i * 16 + rsel) * 32 + rch * 8]);
      bfr[i] = *reinterpret_cast<const s8v*>(
          &Bs[cur][(wc * 64 + i * 16 + rsel) * 32 + rch * 8]);
    }
#pragma unroll
    for (int i = 0; i < 4; ++i)
#pragma unroll
      for (int j = 0; j < 4; ++j)
        acc[i][j] = __builtin_amdgcn_mfma_f32_16x16x32_bf16(af[i], bfr[j], acc[i][j], 0, 0, 0);
    __syncthreads();
    cur = nxt;
  }

  const int mbase = bm0 + wr * 64 + ((lane >> 4) << 2);
  const int cbase = bn0 + wc * 64 + (lane & 15);
#pragma unroll
  for (int j = 0; j < 4; ++j) {
    int c = cbase + j * 16;
    bool primary = (MODE == 2) || (c < 128);
    int cc = primary ? c : c - 128;
    float bv = primary ? bias0[cc] : bias1[cc];
    u16* dst = primary ? out0 : out1;
#pragma unroll
    for (int i = 0; i < 4; ++i) {
#pragma unroll
      for (int r = 0; r < 4; ++r) {
        float x = acc[i][j][r] + bv;
        float v = (MODE == 1) ? (1.f / (1.f + __expf(-x))) : tanhf(x);
        dst[(size_t)(mbase + i * 16 + r) * 128 + cc] = f2bf(v);
      }
    }
  }
}

// ---------------- cand: multiply h-features by r in both layouts ----------------
__global__ __launch_bounds__(256) void cand_kernel(u16* __restrict__ grows,
                                                   char* __restrict__ gt0q,
                                                   const u16* __restrict__ rbuf) {
  const int t = threadIdx.x;
  const int n0 = blockIdx.x * 64;
  const int b = blockIdx.y;
  {
    int n = n0 + (t >> 2);
    int d0 = (t & 3) << 5;
    size_t row = (size_t)n * 16 + b;
#pragma unroll
    for (int q = 0; q < 4; ++q) {
      int d = d0 + q * 8;
      uint4 rv = *reinterpret_cast<const uint4*>(&rbuf[row * 128 + d]);
      uint4 gv = *reinterpret_cast<const uint4*>(&grows[row * 480 + 32 + d]);
      const u16* rp = reinterpret_cast<const u16*>(&rv);
      const u16* gp = reinterpret_cast<const u16*>(&gv);
      uint4 ov;
      u16* op = reinterpret_cast<u16*>(&ov);
#pragma unroll
      for (int i = 0; i < 8; ++i) op[i] = f2bf(bf2f(gp[i]) * bf2f(rp[i]));
      *reinterpret_cast<uint4*>(&grows[row * 480 + 32 + d]) = ov;
    }
  }
  {
    int d = t >> 1;
    int nh = (t & 1) << 5;
    size_t crow = (size_t)b * 160 + 32 + d;
#pragma unroll
    for (int q = 0; q < 4; ++q) {
      int nn = n0 + nh + q * 8;
      uint2 gv = *reinterpret_cast<const uint2*>(&gt0q[crow * 4096 + nn]);
      const char* gp = reinterpret_cast<const char*>(&gv);
      uint2 ov;
      char* op = reinterpret_cast<char*>(&ov);
#pragma unroll
      for (int i = 0; i < 8; ++i) {
        float rv = bf2f(rbuf[((size_t)(nn + i) * 16 + b) * 128 + d]);
        op[i] = (char)(int)__builtin_rintf(rv * (float)gp[i]);
      }
      *reinterpret_cast<uint2*>(&gt0q[crow * 4096 + nn]) = ov;
    }
  }
}

// ---------------- final: GRU combine + LayerNorm ----------------
__global__ __launch_bounds__(256) void final_kernel(const u16* __restrict__ ht,
                                                    const u16* __restrict__ zbuf,
                                                    const float* __restrict__ h_prev,
                                                    const float* __restrict__ gamma,
                                                    const float* __restrict__ beta,
                                                    float* __restrict__ out) {
  const int lane = threadIdx.x & 63, wid = threadIdx.x >> 6;
  const size_t row = (size_t)blockIdx.x * 4 + wid;  // n*16+b
  const int b = (int)(row & 15), n = (int)(row >> 4);
  const int d0 = lane * 2;
  u32 hv = *reinterpret_cast<const u32*>(&ht[row * 128 + d0]);
  u32 zv = *reinterpret_cast<const u32*>(&zbuf[row * 128 + d0]);
  float2 hp = *reinterpret_cast<const float2*>(&h_prev[((size_t)b * 4096 + n) * 128 + d0]);
  float z0 = bf2f((u16)(zv & 0xFFFF)), z1 = bf2f((u16)(zv >> 16));
  float t0 = bf2f((u16)(hv & 0xFFFF)), t1 = bf2f((u16)(hv >> 16));
  float h0 = (1.f - z0) * hp.x + z0 * t0;
  float h1 = (1.f - z1) * hp.y + z1 * t1;
  float s = h0 + h1, ss = h0 * h0 + h1 * h1;
#pragma unroll
  for (int off = 32; off >= 1; off >>= 1) {
    s += __shfl_xor(s, off);
    ss += __shfl_xor(ss, off);
  }
  float mu = s * (1.f / 128.f);
  float var = ss * (1.f / 128.f) - mu * mu;
  float rstd = rsqrtf(var + 1e-5f);
  float2 gv = *reinterpret_cast<const float2*>(&gamma[d0]);
  float2 bv = *reinterpret_cast<const float2*>(&beta[d0]);
  float o0 = (h0 - mu) * rstd * gv.x + bv.x;
  float o1 = (h1 - mu) * rstd * gv.y + bv.y;
  *reinterpret_cast<float2*>(&out[((size_t)b * 4096 + n) * 128 + d0]) =
      make_float2(o0, o1);
}

extern "C" void kernel_launch(void* const* d_in, const int* in_sizes, int n_in,
                              void* d_out, int out_size, void* d_ws, size_t ws_size,
                              hipStream_t stream) {
  const float* x_t = (const float*)d_in[0];
  const float* h_prev = (const float*)d_in[1];
  const float* adj = (const float*)d_in[2];
  const float* Wz = (const float*)d_in[3];
  const float* bz = (const float*)d_in[4];
  const float* Wr = (const float*)d_in[5];
  const float* br = (const float*)d_in[6];
  const float* Wh = (const float*)d_in[7];
  const float* bh = (const float*)d_in[8];
  const float* gamma = (const float*)d_in[9];
  const float* beta = (const float*)d_in[10];
  float* out = (float*)d_out;

  if (ws_size < (size_t)151363584) return;

  char* ws = (char*)d_ws;
  char* adjq = ws;                              // 16,777,216 B (i8, adj*2^18)
  char* gt0q = ws + 16777216;                   // 10,485,760 B (i8, *16)
  char* gt1q = ws + 27262976;                   // 10,485,760 B (i8, hop*2^10)
  u16* grows = (u16*)(ws + 37748736);           // 62,914,560 B
  u16* zbuf = (u16*)(ws + 100663296);           // 16,777,216 B
  u16* rbuf = (u16*)(ws + 117440512);           // 16,777,216 B
  u16* htb = (u16*)(ws + 134217728);            // 16,777,216 B
  u16* wzr = (u16*)(ws + 150994944);            // 245,760 B
  u16* whb = (u16*)(ws + 151240704);            // 122,880 B

  // descales: A=2^18, xh-B=2^4 -> hop1 true = acc*2^-22 ; hop-B=2^10 -> hop2 = acc*2^-28
  const float D22 = 1.f / 4194304.f, D28 = 1.f / 268435456.f, D12 = 1.f / 4096.f;

  dim3 blk(256);
  cvt_adj_i8<<<dim3(16384), blk, 0, stream>>>(adj, (u32*)adjq, 4194304);
  cvt_w3<<<dim3(180), blk, 0, stream>>>(Wz, Wr, Wh, wzr, whb);
  prep_kernel<<<dim3(64, 16), blk, 0, stream>>>(x_t, h_prev, gt0q, grows);
  // phase 1 diffusion (1D grid, XCD slab swizzle; 1280 % 8 == 0 -> 5 blocks/CU)
  gemm_mix_i8<0, 1><<<dim3(1280), blk, 0, stream>>>(adjq, gt0q, gt1q,
                                                    grows + 160, D22, D12);
  gemm_mix_i8<0, 0><<<dim3(1280), blk, 0, stream>>>(adjq, gt1q, nullptr,
                                                    grows + 320, D28, 0.f);
  // z, r gates
  gemm_gate<1><<<dim3(512, 2), blk, 0, stream>>>(grows, wzr, zbuf, rbuf, bz, br);
  // cand: multiply h-features by r (both layouts)
  cand_kernel<<<dim3(64, 16), blk, 0, stream>>>(grows, gt0q, rbuf);
  // phase 2 diffusion (h-channels only; 1024 % 8 == 0 -> 4 blocks/CU)
  gemm_mix_i8<1, 1><<<dim3(1024), blk, 0, stream>>>(adjq, gt0q, gt1q,
                                                    grows + 160, D22, D12);
  gemm_mix_i8<1, 0><<<dim3(1024), blk, 0, stream>>>(adjq, gt1q, nullptr,
                                                    grows + 320, D28, 0.f);
  // h_tilde
  gemm_gate<2><<<dim3(512, 1), blk, 0, stream>>>(grows, whb, htb, nullptr, bh, nullptr);
  final_kernel<<<dim3(16384), blk, 0, stream>>>(htb, zbuf, h_prev, gamma, beta, out);
}

// Round 11
// 337.132 us; speedup vs baseline: 1.6881x; 1.6881x over previous
//
#include <hip/hip_runtime.h>

typedef unsigned short u16;
typedef unsigned int u32;
typedef short s8v __attribute__((ext_vector_type(8)));
typedef float f4v __attribute__((ext_vector_type(4)));
typedef int i4v __attribute__((ext_vector_type(4)));

__device__ __forceinline__ u16 f2bf(float f) {
  u32 u = __builtin_bit_cast(u32, f);
  u32 r = (u + 0x7FFFu + ((u >> 16) & 1u)) >> 16;
  return (u16)r;
}
__device__ __forceinline__ float bf2f(u16 h) {
  u32 u = ((u32)h) << 16;
  return __builtin_bit_cast(float, u);
}
__device__ __forceinline__ int q8(float x) {
  return (int)__builtin_rintf(fmaxf(-127.f, fminf(127.f, x)));
}

// async global->LDS, 16B per lane; LDS dest is wave-uniform base + lane*16
__device__ __forceinline__ void gload16(const void* g, void* l) {
  __builtin_amdgcn_global_load_lds(
      (const __attribute__((address_space(1))) void*)g,
      (__attribute__((address_space(3))) void*)l, 16, 0, 0);
}

// ---------------- fused weight converts: Wz,Wr -> wzr ; Wh -> whb ----------------
__global__ __launch_bounds__(256) void cvt_w3(const float* __restrict__ Wz,
                                              const float* __restrict__ Wr,
                                              const float* __restrict__ Wh,
                                              u16* __restrict__ wzr,
                                              u16* __restrict__ whb) {
  int i = blockIdx.x * 256 + threadIdx.x;
  if (i >= 46080) return;
  const float* src;
  u16* dst;
  int j;
  if (i < 15360) {
    src = Wz; dst = wzr; j = i;
  } else if (i < 30720) {
    src = Wr; dst = wzr + 61440; j = i - 15360;
  } else {
    src = Wh; dst = whb; j = i - 30720;
  }
  float4 v = *reinterpret_cast<const float4*>(&src[j * 4]);
  u16 o0 = f2bf(v.x), o1 = f2bf(v.y), o2 = f2bf(v.z), o3 = f2bf(v.w);
  *reinterpret_cast<uint2*>(&dst[j * 4]) =
      make_uint2(o0 | ((u32)o1 << 16), o2 | ((u32)o3 << 16));
}

// ---------------- adj f32 -> i8 (value * 2^18; adj < 2^-12 so fits in [0,64]) ----
__global__ __launch_bounds__(256) void cvt_adj_i8(const float* __restrict__ in,
                                                  u32* __restrict__ out, int n4) {
  int i = blockIdx.x * 256 + threadIdx.x;
  if (i >= n4) return;
  float4 v = reinterpret_cast<const float4*>(in)[i];
  const float s = 262144.f;  // 2^18
  int a = (int)__builtin_rintf(v.x * s), b = (int)__builtin_rintf(v.y * s);
  int c = (int)__builtin_rintf(v.z * s), d = (int)__builtin_rintf(v.w * s);
  out[i] = (u32)(a & 255) | ((u32)(b & 255) << 8) | ((u32)(c & 255) << 16) |
           ((u32)(d & 255) << 24);
}

// ---------------- prep: xh -> grows (bf16 rows) + gt0q (i8*16, transposed) ------
__global__ __launch_bounds__(256) void prep_kernel(const float* __restrict__ x_t,
                                                   const float* __restrict__ h_prev,
                                                   char* __restrict__ gt0q,
                                                   u16* __restrict__ grows) {
  __shared__ char T8[160][80];
  const int t = threadIdx.x;
  const int n0 = blockIdx.x * 64;
  const int b = blockIdx.y;
#pragma unroll
  for (int q = 0; q < 2; ++q) {
    int idx = t + q * 256;
    int n_loc = idx >> 3, f = (idx & 7) << 2;
    int n = n0 + n_loc;
    float4 v = *reinterpret_cast<const float4*>(&x_t[((size_t)b * 4096 + n) * 32 + f]);
    u16 o[4] = {f2bf(v.x), f2bf(v.y), f2bf(v.z), f2bf(v.w)};
    *reinterpret_cast<uint2*>(&grows[((size_t)n * 16 + b) * 480 + f]) =
        make_uint2(o[0] | ((u32)o[1] << 16), o[2] | ((u32)o[3] << 16));
    T8[f + 0][n_loc] = (char)q8(v.x * 16.f);
    T8[f + 1][n_loc] = (char)q8(v.y * 16.f);
    T8[f + 2][n_loc] = (char)q8(v.z * 16.f);
    T8[f + 3][n_loc] = (char)q8(v.w * 16.f);
  }
#pragma unroll
  for (int q = 0; q < 8; ++q) {
    int idx = t + q * 256;
    int n_loc = idx >> 5, f = (idx & 31) << 2;
    int n = n0 + n_loc;
    float4 v = *reinterpret_cast<const float4*>(&h_prev[((size_t)b * 4096 + n) * 128 + f]);
    u16 o[4] = {f2bf(v.x), f2bf(v.y), f2bf(v.z), f2bf(v.w)};
    *reinterpret_cast<uint2*>(&grows[((size_t)n * 16 + b) * 480 + 32 + f]) =
        make_uint2(o[0] | ((u32)o[1] << 16), o[2] | ((u32)o[3] << 16));
    T8[32 + f + 0][n_loc] = (char)q8(v.x * 16.f);
    T8[32 + f + 1][n_loc] = (char)q8(v.y * 16.f);
    T8[32 + f + 2][n_loc] = (char)q8(v.z * 16.f);
    T8[32 + f + 3][n_loc] = (char)q8(v.w * 16.f);
  }
  __syncthreads();
  if (t < 160) {
    char* dst = &gt0q[((size_t)b * 160 + t) * 4096 + n0];
    const char* src = &T8[t][0];
#pragma unroll
    for (int q = 0; q < 4; ++q)
      reinterpret_cast<uint4*>(dst)[q] = *reinterpret_cast<const uint4*>(src + q * 16);
  }
}

// ------------- mix GEMM i8 (r8-proven): hybrid staging, 8-wave 128x128 ---------
// A via global_load_lds DMA (depth-2 triple-buffer); B via global_load->reg->
// ds_write double-buffer. The compiler's auto-wait before ds_write (vmcnt(2))
// retires A(t+1); A/B(t+2) stay in flight across the barrier (counted, never 0).
// LDS chunk swizzle c ^ ((row>>1)&3) on source + read (conflict-free).
template <int CAND, int WT>
__global__ __launch_bounds__(512) void gemm_mix_i8(const char* __restrict__ A,
                                                   const char* __restrict__ Bt,
                                                   char* __restrict__ outq,
                                                   u16* __restrict__ grows_slice,
                                                   float desc, float qdesc) {
  __shared__ char Ab[3][8192];  // A[128][64] per slot, depth-2 DMA
  __shared__ char Bb[2][8192];  // B[128][64] per slot, reg-staged dbuf
  const int tid = threadIdx.x;
  const int lane = tid & 63, wid = tid >> 6;
  const int wr = wid >> 2, wc = wid & 3;

  const int flat = blockIdx.x;
  const int xcd = flat & 7, r = flat >> 3;
  const int bx = (xcd << 2) | (r & 3), by = r >> 2;
  const int bm0 = bx * 128;
  const int bn0 = CAND ? (by * 160 + 32) : (by * 128);

  const int gchunk = (lane & 3) ^ ((lane >> 3) & 3);
  const int srow = wid * 16 + (lane >> 2);
  const char* aptr = &A[(size_t)(bm0 + srow) * 4096 + gchunk * 16];
  const char* bptr = &Bt[(size_t)(bn0 + srow) * 4096 + gchunk * 16];
  const int lws = wid * 1024;        // wave slice offset within a slot
  const int lwl = lws + lane * 16;   // this lane's ds_write offset

  i4v acc[4][2];
#pragma unroll
  for (int i = 0; i < 4; ++i)
#pragma unroll
    for (int j = 0; j < 2; ++j) acc[i][j] = (i4v){0, 0, 0, 0};

  const int rsel = lane & 15;
  const int rch = (lane >> 4) ^ ((rsel >> 1) & 3);  // swizzled read chunk
  const int ra0 = (wr * 64 + rsel) * 64 + rch * 16;  // A frag base (i=0)
  const int rb0 = (wc * 32 + rsel) * 64 + rch * 16;  // B frag base (j=0)

  uint4 bqE, bqO;

  auto COMPUTE = [&](const char* Ac, const char* Bc) {
    i4v af[4], bfr[2];
#pragma unroll
    for (int i = 0; i < 4; ++i)
      af[i] = *reinterpret_cast<const i4v*>(Ac + ra0 + i * 1024);
#pragma unroll
    for (int j = 0; j < 2; ++j)
      bfr[j] = *reinterpret_cast<const i4v*>(Bc + rb0 + j * 1024);
#pragma unroll
    for (int i = 0; i < 4; ++i)
#pragma unroll
      for (int j = 0; j < 2; ++j)
        acc[i][j] =
            __builtin_amdgcn_mfma_i32_16x16x64_i8(af[i], bfr[j], acc[i][j], 0, 0, 0);
  };
  auto BARRIER = [&]() {
    asm volatile("s_waitcnt lgkmcnt(0)" ::: "memory");  // ds_write visible
    __builtin_amdgcn_s_barrier();
    __builtin_amdgcn_sched_barrier(0);
  };

  // prologue: A tiles 0,1 via DMA; B tiles 0,1 into regs; write B0
  gload16(aptr + 0, &Ab[0][0] + lws);
  bqE = *reinterpret_cast<const uint4*>(bptr + 0);
  gload16(aptr + 64, &Ab[1][0] + lws);
  bqO = *reinterpret_cast<const uint4*>(bptr + 64);
  *reinterpret_cast<uint4*>(&Bb[0][0] + lwl) = bqE;  // auto-waits bqE (A0 retired)
  BARRIER();

  char *Ac = &Ab[0][0], *An = &Ab[1][0], *Af = &Ab[2][0];
  char *Bc = &Bb[0][0], *Bo = &Bb[1][0];
  // 31 pairs: tiles t=0..61, staging t+2 = 2..63
  for (int p = 0; p < 31; ++p) {
    const int k0 = p * 128;
    // even tile t=2p
    gload16(aptr + (k0 + 128), Af + lws);
    bqE = *reinterpret_cast<const uint4*>(bptr + (k0 + 128));
    COMPUTE(Ac, Bc);
    *reinterpret_cast<uint4*>(Bo + lwl) = bqO;  // B(t+1); auto vmcnt retires A(t+1)
    BARRIER();
    { char* ta = Ac; Ac = An; An = Af; Af = ta; }
    { char* tb = Bc; Bc = Bo; Bo = tb; }
    // odd tile t=2p+1
    gload16(aptr + (k0 + 192), Af + lws);
    bqO = *reinterpret_cast<const uint4*>(bptr + (k0 + 192));
    COMPUTE(Ac, Bc);
    *reinterpret_cast<uint4*>(Bo + lwl) = bqE;
    BARRIER();
    { char* ta = Ac; Ac = An; An = Af; Af = ta; }
    { char* tb = Bc; Bc = Bo; Bo = tb; }
  }
  // tail: tiles 62, 63
  COMPUTE(Ac, Bc);
  *reinterpret_cast<uint4*>(Bo + lwl) = bqO;  // B(63); auto-wait retires A(63) too
  BARRIER();
  COMPUTE(An, Bo);

  const int mbase = bm0 + wr * 64 + ((lane >> 4) << 2);
  const int cbase = bn0 + wc * 32 + (lane & 15);
#pragma unroll
  for (int j = 0; j < 2; ++j) {
    int c = cbase + j * 16;
    int cb = c / 160;
    int cf = c - cb * 160;
#pragma unroll
    for (int i = 0; i < 4; ++i) {
      int m = mbase + i * 16;
      float f[4];
#pragma unroll
      for (int q = 0; q < 4; ++q) f[q] = (float)acc[i][j][q] * desc;
      if (WT) {
        int q0 = q8((float)acc[i][j][0] * qdesc), q1 = q8((float)acc[i][j][1] * qdesc);
        int q2 = q8((float)acc[i][j][2] * qdesc), q3 = q8((float)acc[i][j][3] * qdesc);
        *reinterpret_cast<u32*>(&outq[(size_t)c * 4096 + m]) =
            (u32)(q0 & 255) | ((u32)(q1 & 255) << 8) | ((u32)(q2 & 255) << 16) |
            ((u32)(q3 & 255) << 24);
      }
#pragma unroll
      for (int q = 0; q < 4; ++q)
        grows_slice[((size_t)(m + q) * 16 + cb) * 480 + cf] = f2bf(f[q]);
    }
  }
}

// ---------------- z/r gate GEMM (bf16, 2-phase + swizzle) ----------------------
// c<128 -> sigmoid+bias0 -> out0 ; else sigmoid+bias1 -> out1
__global__ __launch_bounds__(256) void gemm_gate_zr(const u16* __restrict__ A,
                                                    const u16* __restrict__ Bt,
                                                    u16* __restrict__ out0,
                                                    u16* __restrict__ out1,
                                                    const float* __restrict__ bias0,
                                                    const float* __restrict__ bias1) {
  __shared__ u16 As[2][128 * 32];
  __shared__ u16 Bs[2][128 * 32];
  const int tid = threadIdx.x;
  const int lane = tid & 63, wid = tid >> 6;
  const int wr = wid >> 1, wc = wid & 1;
  const int bm0 = blockIdx.x * 128, bn0 = blockIdx.y * 128;

  const int gchunk = (lane & 3) ^ ((lane >> 3) & 3);
  const u16* aptr = &A[(size_t)(bm0 + wid * 32 + (lane >> 2)) * 480 + gchunk * 8];
  const u16* bptr = &Bt[(size_t)(bn0 + wid * 32 + (lane >> 2)) * 480 + gchunk * 8];

  f4v acc[4][4];
#pragma unroll
  for (int i = 0; i < 4; ++i)
#pragma unroll
    for (int j = 0; j < 4; ++j) acc[i][j] = (f4v){0.f, 0.f, 0.f, 0.f};

  const int rsel = lane & 15;
  const int rch = (lane >> 4) ^ ((rsel >> 1) & 3);

#pragma unroll
  for (int q = 0; q < 2; ++q) {
    gload16(aptr + (size_t)q * 16 * 480, &As[0][wid * 1024 + q * 512]);
    gload16(bptr + (size_t)q * 16 * 480, &Bs[0][wid * 1024 + q * 512]);
  }
  __syncthreads();

  int cur = 0;
  for (int k0 = 0; k0 < 480; k0 += 32) {
    const int nxt = cur ^ 1;
    if (k0 + 32 < 480) {
#pragma unroll
      for (int q = 0; q < 2; ++q) {
        gload16(aptr + (size_t)q * 16 * 480 + (k0 + 32), &As[nxt][wid * 1024 + q * 512]);
        gload16(bptr + (size_t)q * 16 * 480 + (k0 + 32), &Bs[nxt][wid * 1024 + q * 512]);
      }
    }
    s8v af[4], bfr[4];
#pragma unroll
    for (int i = 0; i < 4; ++i) {
      af[i] = *reinterpret_cast<const s8v*>(
          &As[cur][(wr * 64 + i * 16 + rsel) * 32 + rch * 8]);
      bfr[i] = *reinterpret_cast<const s8v*>(
          &Bs[cur][(wc * 64 + i * 16 + rsel) * 32 + rch * 8]);
    }
#pragma unroll
    for (int i = 0; i < 4; ++i)
#pragma unroll
      for (int j = 0; j < 4; ++j)
        acc[i][j] = __builtin_amdgcn_mfma_f32_16x16x32_bf16(af[i], bfr[j], acc[i][j], 0, 0, 0);
    __syncthreads();
    cur = nxt;
  }

  const int mbase = bm0 + wr * 64 + ((lane >> 4) << 2);
  const int cbase = bn0 + wc * 64 + (lane & 15);
#pragma unroll
  for (int j = 0; j < 4; ++j) {
    int c = cbase + j * 16;
    bool primary = (c < 128);
    int cc = primary ? c : c - 128;
    float bv = primary ? bias0[cc] : bias1[cc];
    u16* dst = primary ? out0 : out1;
#pragma unroll
    for (int i = 0; i < 4; ++i) {
#pragma unroll
      for (int r = 0; r < 4; ++r) {
        float x = acc[i][j][r] + bv;
        float v = 1.f / (1.f + __expf(-x));
        dst[(size_t)(mbase + i * 16 + r) * 128 + cc] = f2bf(v);
      }
    }
  }
}

// ------- h-gate GEMM + fused GRU combine + LayerNorm (writes final f32 out) ----
// Block = 128 rows x full d=128. tanh(G@Wh^T+bh) -> h = (1-z)h_prev + z h~ ->
// LN over d (block-local: per-lane j-partials, shfl over rsel group, LDS
// exchange between the two wave-columns) -> out f32.
__global__ __launch_bounds__(256) void gemm_gate_h(const u16* __restrict__ A,
                                                   const u16* __restrict__ Bt,
                                                   const u16* __restrict__ zbuf,
                                                   const float* __restrict__ h_prev,
                                                   const float* __restrict__ bias,
                                                   const float* __restrict__ gamma,
                                                   const float* __restrict__ beta,
                                                   float* __restrict__ out) {
  __shared__ u16 As[2][128 * 32];
  __shared__ u16 Bs[2][128 * 32];
  __shared__ float redS[128][2];
  __shared__ float redSS[128][2];
  const int tid = threadIdx.x;
  const int lane = tid & 63, wid = tid >> 6;
  const int wr = wid >> 1, wc = wid & 1;
  const int bm0 = blockIdx.x * 128;

  const int gchunk = (lane & 3) ^ ((lane >> 3) & 3);
  const u16* aptr = &A[(size_t)(bm0 + wid * 32 + (lane >> 2)) * 480 + gchunk * 8];
  const u16* bptr = &Bt[(size_t)(wid * 32 + (lane >> 2)) * 480 + gchunk * 8];

  f4v acc[4][4];
#pragma unroll
  for (int i = 0; i < 4; ++i)
#pragma unroll
    for (int j = 0; j < 4; ++j) acc[i][j] = (f4v){0.f, 0.f, 0.f, 0.f};

  const int rsel = lane & 15;
  const int rch = (lane >> 4) ^ ((rsel >> 1) & 3);

#pragma unroll
  for (int q = 0; q < 2; ++q) {
    gload16(aptr + (size_t)q * 16 * 480, &As[0][wid * 1024 + q * 512]);
    gload16(bptr + (size_t)q * 16 * 480, &Bs[0][wid * 1024 + q * 512]);
  }
  __syncthreads();

  int cur = 0;
  for (int k0 = 0; k0 < 480; k0 += 32) {
    const int nxt = cur ^ 1;
    if (k0 + 32 < 480) {
#pragma unroll
      for (int q = 0; q < 2; ++q) {
        gload16(aptr + (size_t)q * 16 * 480 + (k0 + 32), &As[nxt][wid * 1024 + q * 512]);
        gload16(bptr + (size_t)q * 16 * 480 + (k0 + 32), &Bs[nxt][wid * 1024 + q * 512]);
      }
    }
    s8v af[4], bfr[4];
#pragma unroll
    for (int i = 0; i < 4; ++i) {
      af[i] = *reinterpret_cast<const s8v*>(
          &As[cur][(wr * 64 + i * 16 + rsel) * 32 + rch * 8]);
      bfr[i] = *reinterpret_cast<const s8v*>(
          &Bs[cur][(wc * 64 + i * 16 + rsel) * 32 + rch * 8]);
    }
#pragma unroll
    for (int i = 0; i < 4; ++i)
#pragma unroll
      for (int j = 0; j < 4; ++j)
        acc[i][j] = __builtin_amdgcn_mfma_f32_16x16x32_bf16(af[i], bfr[j], acc[i][j], 0, 0, 0);
    __syncthreads();
    cur = nxt;
  }

  // ---- epilogue: h = (1-z)h_prev + z tanh(x+b); LN over d=128 ----
  const int mlb = wr * 64 + ((lane >> 4) << 2);  // m_loc for (i=0, r=0)
  const int cbase = wc * 64 + rsel;              // c for j=0
  float sv[4][4], ssv[4][4];
#pragma unroll
  for (int i = 0; i < 4; ++i)
#pragma unroll
    for (int r = 0; r < 4; ++r) {
      sv[i][r] = 0.f;
      ssv[i][r] = 0.f;
    }
#pragma unroll
  for (int j = 0; j < 4; ++j) {
    int c = cbase + j * 16;
    float bv = bias[c];
#pragma unroll
    for (int i = 0; i < 4; ++i) {
#pragma unroll
      for (int r = 0; r < 4; ++r) {
        int m = bm0 + mlb + i * 16 + r;
        float x = acc[i][j][r] + bv;
        float ht = tanhf(x);
        float z = bf2f(zbuf[(size_t)m * 128 + c]);
        int n = m >> 4, b = m & 15;
        float hp = h_prev[((size_t)b * 4096 + n) * 128 + c];
        float h = (1.f - z) * hp + z * ht;
        acc[i][j][r] = h;  // keep h in place of the accumulator
        sv[i][r] += h;
        ssv[i][r] += h * h;
      }
    }
  }
  // reduce over the 16-lane rsel group (c axis within the wave)
#pragma unroll
  for (int i = 0; i < 4; ++i)
#pragma unroll
    for (int r = 0; r < 4; ++r) {
      float s = sv[i][r], ss = ssv[i][r];
#pragma unroll
      for (int off = 1; off <= 8; off <<= 1) {
        s += __shfl_xor(s, off);
        ss += __shfl_xor(ss, off);
      }
      sv[i][r] = s;
      ssv[i][r] = ss;
    }
  if (rsel == 0) {
#pragma unroll
    for (int i = 0; i < 4; ++i)
#pragma unroll
      for (int r = 0; r < 4; ++r) {
        int ml = mlb + i * 16 + r;
        redS[ml][wc] = sv[i][r];
        redSS[ml][wc] = ssv[i][r];
      }
  }
  __syncthreads();
#pragma unroll
  for (int i = 0; i < 4; ++i) {
#pragma unroll
    for (int r = 0; r < 4; ++r) {
      int ml = mlb + i * 16 + r;
      float s = redS[ml][0] + redS[ml][1];
      float ss = redSS[ml][0] + redSS[ml][1];
      float mu = s * (1.f / 128.f);
      float var = ss * (1.f / 128.f) - mu * mu;
      float rstd = rsqrtf(var + 1e-5f);
      int m = bm0 + ml;
      int n = m >> 4, b = m & 15;
#pragma unroll
      for (int j = 0; j < 4; ++j) {
        int c = cbase + j * 16;
        out[((size_t)b * 4096 + n) * 128 + c] =
            (acc[i][j][r] - mu) * rstd * gamma[c] + beta[c];
      }
    }
  }
}

// ---------------- cand: multiply h-features by r in both layouts ----------------
__global__ __launch_bounds__(256) void cand_kernel(u16* __restrict__ grows,
                                                   char* __restrict__ gt0q,
                                                   const u16* __restrict__ rbuf) {
  const int t = threadIdx.x;
  const int n0 = blockIdx.x * 64;
  const int b = blockIdx.y;
  {
    int n = n0 + (t >> 2);
    int d0 = (t & 3) << 5;
    size_t row = (size_t)n * 16 + b;
#pragma unroll
    for (int q = 0; q < 4; ++q) {
      int d = d0 + q * 8;
      uint4 rv = *reinterpret_cast<const uint4*>(&rbuf[row * 128 + d]);
      uint4 gv = *reinterpret_cast<const uint4*>(&grows[row * 480 + 32 + d]);
      const u16* rp = reinterpret_cast<const u16*>(&rv);
      const u16* gp = reinterpret_cast<const u16*>(&gv);
      uint4 ov;
      u16* op = reinterpret_cast<u16*>(&ov);
#pragma unroll
      for (int i = 0; i < 8; ++i) op[i] = f2bf(bf2f(gp[i]) * bf2f(rp[i]));
      *reinterpret_cast<uint4*>(&grows[row * 480 + 32 + d]) = ov;
    }
  }
  {
    int d = t >> 1;
    int nh = (t & 1) << 5;
    size_t crow = (size_t)b * 160 + 32 + d;
#pragma unroll
    for (int q = 0; q < 4; ++q) {
      int nn = n0 + nh + q * 8;
      uint2 gv = *reinterpret_cast<const uint2*>(&gt0q[crow * 4096 + nn]);
      const char* gp = reinterpret_cast<const char*>(&gv);
      uint2 ov;
      char* op = reinterpret_cast<char*>(&ov);
#pragma unroll
      for (int i = 0; i < 8; ++i) {
        float rv = bf2f(rbuf[((size_t)(nn + i) * 16 + b) * 128 + d]);
        op[i] = (char)(int)__builtin_rintf(rv * (float)gp[i]);
      }
      *reinterpret_cast<uint2*>(&gt0q[crow * 4096 + nn]) = ov;
    }
  }
}

extern "C" void kernel_launch(void* const* d_in, const int* in_sizes, int n_in,
                              void* d_out, int out_size, void* d_ws, size_t ws_size,
                              hipStream_t stream) {
  const float* x_t = (const float*)d_in[0];
  const float* h_prev = (const float*)d_in[1];
  const float* adj = (const float*)d_in[2];
  const float* Wz = (const float*)d_in[3];
  const float* bz = (const float*)d_in[4];
  const float* Wr = (const float*)d_in[5];
  const float* br = (const float*)d_in[6];
  const float* Wh = (const float*)d_in[7];
  const float* bh = (const float*)d_in[8];
  const float* gamma = (const float*)d_in[9];
  const float* beta = (const float*)d_in[10];
  float* out = (float*)d_out;

  if (ws_size < (size_t)151363584) return;

  char* ws = (char*)d_ws;
  char* adjq = ws;                              // 16,777,216 B (i8, adj*2^18)
  char* gt0q = ws + 16777216;                   // 10,485,760 B (i8, *16)
  char* gt1q = ws + 27262976;                   // 10,485,760 B (i8, hop*2^10)
  u16* grows = (u16*)(ws + 37748736);           // 62,914,560 B
  u16* zbuf = (u16*)(ws + 100663296);           // 16,777,216 B
  u16* rbuf = (u16*)(ws + 117440512);           // 16,777,216 B
  u16* wzr = (u16*)(ws + 150994944);            // 245,760 B
  u16* whb = (u16*)(ws + 151240704);            // 122,880 B

  // descales: A=2^18, xh-B=2^4 -> hop1 true = acc*2^-22 ; hop-B=2^10 -> hop2 = acc*2^-28
  const float D22 = 1.f / 4194304.f, D28 = 1.f / 268435456.f, D12 = 1.f / 4096.f;

  dim3 blk(256);
  cvt_adj_i8<<<dim3(16384), blk, 0, stream>>>(adj, (u32*)adjq, 4194304);
  cvt_w3<<<dim3(180), blk, 0, stream>>>(Wz, Wr, Wh, wzr, whb);
  prep_kernel<<<dim3(64, 16), blk, 0, stream>>>(x_t, h_prev, gt0q, grows);
  // phase 1 diffusion (1D grid, XCD M-slab swizzle; 640 % 8 == 0)
  gemm_mix_i8<0, 1><<<dim3(640), dim3(512), 0, stream>>>(adjq, gt0q, gt1q,
                                                         grows + 160, D22, D12);
  gemm_mix_i8<0, 0><<<dim3(640), dim3(512), 0, stream>>>(adjq, gt1q, nullptr,
                                                         grows + 320, D28, 0.f);
  // z, r gates
  gemm_gate_zr<<<dim3(512, 2), blk, 0, stream>>>(grows, wzr, zbuf, rbuf, bz, br);
  // cand: multiply h-features by r (both layouts)
  cand_kernel<<<dim3(64, 16), blk, 0, stream>>>(grows, gt0q, rbuf);
  // phase 2 diffusion (h-channels only; 512 % 8 == 0)
  gemm_mix_i8<1, 1><<<dim3(512), dim3(512), 0, stream>>>(adjq, gt0q, gt1q,
                                                         grows + 160, D22, D12);
  gemm_mix_i8<1, 0><<<dim3(512), dim3(512), 0, stream>>>(adjq, gt1q, nullptr,
                                                         grows + 320, D28, 0.f);
  // h_tilde + GRU combine + LayerNorm fused (writes final f32 output)
  gemm_gate_h<<<dim3(512), blk, 0, stream>>>(grows, whb, zbuf, h_prev, bh,
                                             gamma, beta, out);
}

// Round 12
// 324.795 us; speedup vs baseline: 1.7522x; 1.0380x over previous
//
#include <hip/hip_runtime.h>

typedef unsigned short u16;
typedef unsigned int u32;
typedef short s8v __attribute__((ext_vector_type(8)));
typedef float f4v __attribute__((ext_vector_type(4)));
typedef int i4v __attribute__((ext_vector_type(4)));

__device__ __forceinline__ u16 f2bf(float f) {
  u32 u = __builtin_bit_cast(u32, f);
  u32 r = (u + 0x7FFFu + ((u >> 16) & 1u)) >> 16;
  return (u16)r;
}
__device__ __forceinline__ float bf2f(u16 h) {
  u32 u = ((u32)h) << 16;
  return __builtin_bit_cast(float, u);
}
__device__ __forceinline__ int q8(float x) {
  return (int)__builtin_rintf(fmaxf(-127.f, fminf(127.f, x)));
}

// async global->LDS, 16B per lane; LDS dest is wave-uniform base + lane*16
__device__ __forceinline__ void gload16(const void* g, void* l) {
  __builtin_amdgcn_global_load_lds(
      (const __attribute__((address_space(1))) void*)g,
      (__attribute__((address_space(3))) void*)l, 16, 0, 0);
}

// ---------------- fused weight converts: Wz,Wr -> wzr ; Wh -> whb ----------------
__global__ __launch_bounds__(256) void cvt_w3(const float* __restrict__ Wz,
                                              const float* __restrict__ Wr,
                                              const float* __restrict__ Wh,
                                              u16* __restrict__ wzr,
                                              u16* __restrict__ whb) {
  int i = blockIdx.x * 256 + threadIdx.x;
  if (i >= 46080) return;
  const float* src;
  u16* dst;
  int j;
  if (i < 15360) {
    src = Wz; dst = wzr; j = i;
  } else if (i < 30720) {
    src = Wr; dst = wzr + 61440; j = i - 15360;
  } else {
    src = Wh; dst = whb; j = i - 30720;
  }
  float4 v = *reinterpret_cast<const float4*>(&src[j * 4]);
  u16 o0 = f2bf(v.x), o1 = f2bf(v.y), o2 = f2bf(v.z), o3 = f2bf(v.w);
  *reinterpret_cast<uint2*>(&dst[j * 4]) =
      make_uint2(o0 | ((u32)o1 << 16), o2 | ((u32)o3 << 16));
}

// ---------------- adj f32 -> i8 (value * 2^18; adj < 2^-12 so fits in [0,64]) ----
__global__ __launch_bounds__(256) void cvt_adj_i8(const float* __restrict__ in,
                                                  u32* __restrict__ out, int n4) {
  int i = blockIdx.x * 256 + threadIdx.x;
  if (i >= n4) return;
  float4 v = reinterpret_cast<const float4*>(in)[i];
  const float s = 262144.f;  // 2^18
  int a = (int)__builtin_rintf(v.x * s), b = (int)__builtin_rintf(v.y * s);
  int c = (int)__builtin_rintf(v.z * s), d = (int)__builtin_rintf(v.w * s);
  out[i] = (u32)(a & 255) | ((u32)(b & 255) << 8) | ((u32)(c & 255) << 16) |
           ((u32)(d & 255) << 24);
}

// ---------------- prep: xh -> grows (bf16 rows) + gt0q (i8*16, transposed) ------
__global__ __launch_bounds__(256) void prep_kernel(const float* __restrict__ x_t,
                                                   const float* __restrict__ h_prev,
                                                   char* __restrict__ gt0q,
                                                   u16* __restrict__ grows) {
  __shared__ char T8[160][80];
  const int t = threadIdx.x;
  const int n0 = blockIdx.x * 64;
  const int b = blockIdx.y;
#pragma unroll
  for (int q = 0; q < 2; ++q) {
    int idx = t + q * 256;
    int n_loc = idx >> 3, f = (idx & 7) << 2;
    int n = n0 + n_loc;
    float4 v = *reinterpret_cast<const float4*>(&x_t[((size_t)b * 4096 + n) * 32 + f]);
    u16 o[4] = {f2bf(v.x), f2bf(v.y), f2bf(v.z), f2bf(v.w)};
    *reinterpret_cast<uint2*>(&grows[((size_t)n * 16 + b) * 480 + f]) =
        make_uint2(o[0] | ((u32)o[1] << 16), o[2] | ((u32)o[3] << 16));
    T8[f + 0][n_loc] = (char)q8(v.x * 16.f);
    T8[f + 1][n_loc] = (char)q8(v.y * 16.f);
    T8[f + 2][n_loc] = (char)q8(v.z * 16.f);
    T8[f + 3][n_loc] = (char)q8(v.w * 16.f);
  }
#pragma unroll
  for (int q = 0; q < 8; ++q) {
    int idx = t + q * 256;
    int n_loc = idx >> 5, f = (idx & 31) << 2;
    int n = n0 + n_loc;
    float4 v = *reinterpret_cast<const float4*>(&h_prev[((size_t)b * 4096 + n) * 128 + f]);
    u16 o[4] = {f2bf(v.x), f2bf(v.y), f2bf(v.z), f2bf(v.w)};
    *reinterpret_cast<uint2*>(&grows[((size_t)n * 16 + b) * 480 + 32 + f]) =
        make_uint2(o[0] | ((u32)o[1] << 16), o[2] | ((u32)o[3] << 16));
    T8[32 + f + 0][n_loc] = (char)q8(v.x * 16.f);
    T8[32 + f + 1][n_loc] = (char)q8(v.y * 16.f);
    T8[32 + f + 2][n_loc] = (char)q8(v.z * 16.f);
    T8[32 + f + 3][n_loc] = (char)q8(v.w * 16.f);
  }
  __syncthreads();
  if (t < 160) {
    char* dst = &gt0q[((size_t)b * 160 + t) * 4096 + n0];
    const char* src = &T8[t][0];
#pragma unroll
    for (int q = 0; q < 4; ++q)
      reinterpret_cast<uint4*>(dst)[q] = *reinterpret_cast<const uint4*>(src + q * 16);
  }
}

// ------------- mix GEMM i8: hybrid staging (A via global_load_lds DMA, B via
// global_load->reg->ds_write), 8-wave 128x128, counted in-flight loads ----------
// Per tile t: dma_A(t+2); B(t+2)->reg; COMPUTE(t); ds_write B(t+1); barrier.
// The compiler's auto-wait before ds_write (vmcnt(2)) retires A(t+1) (in-order
// vmcnt retirement); A/B(t+2) stay in flight across the barrier (never 0).
// LDS chunk swizzle c ^ ((row>>1)&3) on source + read (conflict-free).
template <int CAND, int WT>
__global__ __launch_bounds__(512) void gemm_mix_i8(const char* __restrict__ A,
                                                   const char* __restrict__ Bt,
                                                   char* __restrict__ outq,
                                                   u16* __restrict__ grows_slice,
                                                   float desc, float qdesc) {
  __shared__ char Ab[3][8192];  // A[128][64] per slot, depth-2 DMA
  __shared__ char Bb[2][8192];  // B[128][64] per slot, reg-staged dbuf
  const int tid = threadIdx.x;
  const int lane = tid & 63, wid = tid >> 6;
  const int wr = wid >> 2, wc = wid & 3;

  const int flat = blockIdx.x;
  const int xcd = flat & 7, r = flat >> 3;
  const int bx = (xcd << 2) | (r & 3), by = r >> 2;
  const int bm0 = bx * 128;
  const int bn0 = CAND ? (by * 160 + 32) : (by * 128);

  const int gchunk = (lane & 3) ^ ((lane >> 3) & 3);
  const int srow = wid * 16 + (lane >> 2);
  const char* aptr = &A[(size_t)(bm0 + srow) * 4096 + gchunk * 16];
  const char* bptr = &Bt[(size_t)(bn0 + srow) * 4096 + gchunk * 16];
  const int lws = wid * 1024;        // wave slice offset within a slot
  const int lwl = lws + lane * 16;   // this lane's ds_write offset

  i4v acc[4][2];
#pragma unroll
  for (int i = 0; i < 4; ++i)
#pragma unroll
    for (int j = 0; j < 2; ++j) acc[i][j] = (i4v){0, 0, 0, 0};

  const int rsel = lane & 15;
  const int rch = (lane >> 4) ^ ((rsel >> 1) & 3);  // swizzled read chunk
  const int ra0 = (wr * 64 + rsel) * 64 + rch * 16;  // A frag base (i=0)
  const int rb0 = (wc * 32 + rsel) * 64 + rch * 16;  // B frag base (j=0)

  uint4 bqE, bqO;

  auto COMPUTE = [&](const char* Ac, const char* Bc) {
    i4v af[4], bfr[2];
#pragma unroll
    for (int i = 0; i < 4; ++i)
      af[i] = *reinterpret_cast<const i4v*>(Ac + ra0 + i * 1024);
#pragma unroll
    for (int j = 0; j < 2; ++j)
      bfr[j] = *reinterpret_cast<const i4v*>(Bc + rb0 + j * 1024);
#pragma unroll
    for (int i = 0; i < 4; ++i)
#pragma unroll
      for (int j = 0; j < 2; ++j)
        acc[i][j] =
            __builtin_amdgcn_mfma_i32_16x16x64_i8(af[i], bfr[j], acc[i][j], 0, 0, 0);
  };
  auto BARRIER = [&]() {
    asm volatile("s_waitcnt lgkmcnt(0)" ::: "memory");  // ds_write visible
    __builtin_amdgcn_s_barrier();
    __builtin_amdgcn_sched_barrier(0);
  };

  // prologue: A tiles 0,1 via DMA; B tiles 0,1 into regs; write B0
  gload16(aptr + 0, &Ab[0][0] + lws);
  bqE = *reinterpret_cast<const uint4*>(bptr + 0);
  gload16(aptr + 64, &Ab[1][0] + lws);
  bqO = *reinterpret_cast<const uint4*>(bptr + 64);
  *reinterpret_cast<uint4*>(&Bb[0][0] + lwl) = bqE;  // auto-waits bqE (A0 retired)
  BARRIER();

  char *Ac = &Ab[0][0], *An = &Ab[1][0], *Af = &Ab[2][0];
  char *Bc = &Bb[0][0], *Bo = &Bb[1][0];
  // 31 pairs: tiles t=0..61, staging t+2 = 2..63
  for (int p = 0; p < 31; ++p) {
    const int k0 = p * 128;
    // even tile t=2p
    gload16(aptr + (k0 + 128), Af + lws);
    bqE = *reinterpret_cast<const uint4*>(bptr + (k0 + 128));
    COMPUTE(Ac, Bc);
    *reinterpret_cast<uint4*>(Bo + lwl) = bqO;  // B(t+1); auto vmcnt retires A(t+1)
    BARRIER();
    { char* ta = Ac; Ac = An; An = Af; Af = ta; }
    { char* tb = Bc; Bc = Bo; Bo = tb; }
    // odd tile t=2p+1
    gload16(aptr + (k0 + 192), Af + lws);
    bqO = *reinterpret_cast<const uint4*>(bptr + (k0 + 192));
    COMPUTE(Ac, Bc);
    *reinterpret_cast<uint4*>(Bo + lwl) = bqE;
    BARRIER();
    { char* ta = Ac; Ac = An; An = Af; Af = ta; }
    { char* tb = Bc; Bc = Bo; Bo = tb; }
  }
  // tail: tiles 62, 63
  COMPUTE(Ac, Bc);
  *reinterpret_cast<uint4*>(Bo + lwl) = bqO;  // B(63); auto-wait retires A(63) too
  BARRIER();
  COMPUTE(An, Bo);

  const int mbase = bm0 + wr * 64 + ((lane >> 4) << 2);
  const int cbase = bn0 + wc * 32 + (lane & 15);
#pragma unroll
  for (int j = 0; j < 2; ++j) {
    int c = cbase + j * 16;
    int cb = c / 160;
    int cf = c - cb * 160;
#pragma unroll
    for (int i = 0; i < 4; ++i) {
      int m = mbase + i * 16;
      float f[4];
#pragma unroll
      for (int q = 0; q < 4; ++q) f[q] = (float)acc[i][j][q] * desc;
      if (WT) {
        int q0 = q8((float)acc[i][j][0] * qdesc), q1 = q8((float)acc[i][j][1] * qdesc);
        int q2 = q8((float)acc[i][j][2] * qdesc), q3 = q8((float)acc[i][j][3] * qdesc);
        *reinterpret_cast<u32*>(&outq[(size_t)c * 4096 + m]) =
            (u32)(q0 & 255) | ((u32)(q1 & 255) << 8) | ((u32)(q2 & 255) << 16) |
            ((u32)(q3 & 255) << 24);
      }
#pragma unroll
      for (int q = 0; q < 4; ++q)
        grows_slice[((size_t)(m + q) * 16 + cb) * 480 + cf] = f2bf(f[q]);
    }
  }
}

// ---------------- gate GEMM (bf16, 2-phase + swizzle) --------------------------
// MODE 1: z/r. c<128 -> sigmoid+bias0 -> out0 ; else sigmoid+bias1 -> out1
// MODE 2: h gate. tanh+bias0 -> out0
template <int MODE>
__global__ __launch_bounds__(256) void gemm_gate(const u16* __restrict__ A,
                                                 const u16* __restrict__ Bt,
                                                 u16* __restrict__ out0,
                                                 u16* __restrict__ out1,
                                                 const float* __restrict__ bias0,
                                                 const float* __restrict__ bias1) {
  __shared__ u16 As[2][128 * 32];
  __shared__ u16 Bs[2][128 * 32];
  const int tid = threadIdx.x;
  const int lane = tid & 63, wid = tid >> 6;
  const int wr = wid >> 1, wc = wid & 1;
  const int bm0 = blockIdx.x * 128, bn0 = blockIdx.y * 128;

  const int gchunk = (lane & 3) ^ ((lane >> 3) & 3);
  const u16* aptr = &A[(size_t)(bm0 + wid * 32 + (lane >> 2)) * 480 + gchunk * 8];
  const u16* bptr = &Bt[(size_t)(bn0 + wid * 32 + (lane >> 2)) * 480 + gchunk * 8];

  f4v acc[4][4];
#pragma unroll
  for (int i = 0; i < 4; ++i)
#pragma unroll
    for (int j = 0; j < 4; ++j) acc[i][j] = (f4v){0.f, 0.f, 0.f, 0.f};

  const int rsel = lane & 15;
  const int rch = (lane >> 4) ^ ((rsel >> 1) & 3);

#pragma unroll
  for (int q = 0; q < 2; ++q) {
    gload16(aptr + (size_t)q * 16 * 480, &As[0][wid * 1024 + q * 512]);
    gload16(bptr + (size_t)q * 16 * 480, &Bs[0][wid * 1024 + q * 512]);
  }
  __syncthreads();

  int cur = 0;
  for (int k0 = 0; k0 < 480; k0 += 32) {
    const int nxt = cur ^ 1;
    if (k0 + 32 < 480) {
#pragma unroll
      for (int q = 0; q < 2; ++q) {
        gload16(aptr + (size_t)q * 16 * 480 + (k0 + 32), &As[nxt][wid * 1024 + q * 512]);
        gload16(bptr + (size_t)q * 16 * 480 + (k0 + 32), &Bs[nxt][wid * 1024 + q * 512]);
      }
    }
    s8v af[4], bfr[4];
#pragma unroll
    for (int i = 0; i < 4; ++i) {
      af[i] = *reinterpret_cast<const s8v*>(
          &As[cur][(wr * 64 + i * 16 + rsel) * 32 + rch * 8]);
      bfr[i] = *reinterpret_cast<const s8v*>(
          &Bs[cur][(wc * 64 + i * 16 + rsel) * 32 + rch * 8]);
    }
#pragma unroll
    for (int i = 0; i < 4; ++i)
#pragma unroll
      for (int j = 0; j < 4; ++j)
        acc[i][j] = __builtin_amdgcn_mfma_f32_16x16x32_bf16(af[i], bfr[j], acc[i][j], 0, 0, 0);
    __syncthreads();
    cur = nxt;
  }

  const int mbase = bm0 + wr * 64 + ((lane >> 4) << 2);
  const int cbase = bn0 + wc * 64 + (lane & 15);
#pragma unroll
  for (int j = 0; j < 4; ++j) {
    int c = cbase + j * 16;
    bool primary = (MODE == 2) || (c < 128);
    int cc = primary ? c : c - 128;
    float bv = primary ? bias0[cc] : bias1[cc];
    u16* dst = primary ? out0 : out1;
#pragma unroll
    for (int i = 0; i < 4; ++i) {
#pragma unroll
      for (int r = 0; r < 4; ++r) {
        float x = acc[i][j][r] + bv;
        float v = (MODE == 1) ? (1.f / (1.f + __expf(-x))) : tanhf(x);
        dst[(size_t)(mbase + i * 16 + r) * 128 + cc] = f2bf(v);
      }
    }
  }
}

// ---------------- cand: multiply h-features by r in both layouts ----------------
__global__ __launch_bounds__(256) void cand_kernel(u16* __restrict__ grows,
                                                   char* __restrict__ gt0q,
                                                   const u16* __restrict__ rbuf) {
  const int t = threadIdx.x;
  const int n0 = blockIdx.x * 64;
  const int b = blockIdx.y;
  {
    int n = n0 + (t >> 2);
    int d0 = (t & 3) << 5;
    size_t row = (size_t)n * 16 + b;
#pragma unroll
    for (int q = 0; q < 4; ++q) {
      int d = d0 + q * 8;
      uint4 rv = *reinterpret_cast<const uint4*>(&rbuf[row * 128 + d]);
      uint4 gv = *reinterpret_cast<const uint4*>(&grows[row * 480 + 32 + d]);
      const u16* rp = reinterpret_cast<const u16*>(&rv);
      const u16* gp = reinterpret_cast<const u16*>(&gv);
      uint4 ov;
      u16* op = reinterpret_cast<u16*>(&ov);
#pragma unroll
      for (int i = 0; i < 8; ++i) op[i] = f2bf(bf2f(gp[i]) * bf2f(rp[i]));
      *reinterpret_cast<uint4*>(&grows[row * 480 + 32 + d]) = ov;
    }
  }
  {
    int d = t >> 1;
    int nh = (t & 1) << 5;
    size_t crow = (size_t)b * 160 + 32 + d;
#pragma unroll
    for (int q = 0; q < 4; ++q) {
      int nn = n0 + nh + q * 8;
      uint2 gv = *reinterpret_cast<const uint2*>(&gt0q[crow * 4096 + nn]);
      const char* gp = reinterpret_cast<const char*>(&gv);
      uint2 ov;
      char* op = reinterpret_cast<char*>(&ov);
#pragma unroll
      for (int i = 0; i < 8; ++i) {
        float rv = bf2f(rbuf[((size_t)(nn + i) * 16 + b) * 128 + d]);
        op[i] = (char)(int)__builtin_rintf(rv * (float)gp[i]);
      }
      *reinterpret_cast<uint2*>(&gt0q[crow * 4096 + nn]) = ov;
    }
  }
}

// ---------------- final: GRU combine + LayerNorm ----------------
__global__ __launch_bounds__(256) void final_kernel(const u16* __restrict__ ht,
                                                    const u16* __restrict__ zbuf,
                                                    const float* __restrict__ h_prev,
                                                    const float* __restrict__ gamma,
                                                    const float* __restrict__ beta,
                                                    float* __restrict__ out) {
  const int lane = threadIdx.x & 63, wid = threadIdx.x >> 6;
  const size_t row = (size_t)blockIdx.x * 4 + wid;  // n*16+b
  const int b = (int)(row & 15), n = (int)(row >> 4);
  const int d0 = lane * 2;
  u32 hv = *reinterpret_cast<const u32*>(&ht[row * 128 + d0]);
  u32 zv = *reinterpret_cast<const u32*>(&zbuf[row * 128 + d0]);
  float2 hp = *reinterpret_cast<const float2*>(&h_prev[((size_t)b * 4096 + n) * 128 + d0]);
  float z0 = bf2f((u16)(zv & 0xFFFF)), z1 = bf2f((u16)(zv >> 16));
  float t0 = bf2f((u16)(hv & 0xFFFF)), t1 = bf2f((u16)(hv >> 16));
  float h0 = (1.f - z0) * hp.x + z0 * t0;
  float h1 = (1.f - z1) * hp.y + z1 * t1;
  float s = h0 + h1, ss = h0 * h0 + h1 * h1;
#pragma unroll
  for (int off = 32; off >= 1; off >>= 1) {
    s += __shfl_xor(s, off);
    ss += __shfl_xor(ss, off);
  }
  float mu = s * (1.f / 128.f);
  float var = ss * (1.f / 128.f) - mu * mu;
  float rstd = rsqrtf(var + 1e-5f);
  float2 gv = *reinterpret_cast<const float2*>(&gamma[d0]);
  float2 bv = *reinterpret_cast<const float2*>(&beta[d0]);
  float o0 = (h0 - mu) * rstd * gv.x + bv.x;
  float o1 = (h1 - mu) * rstd * gv.y + bv.y;
  *reinterpret_cast<float2*>(&out[((size_t)b * 4096 + n) * 128 + d0]) =
      make_float2(o0, o1);
}

extern "C" void kernel_launch(void* const* d_in, const int* in_sizes, int n_in,
                              void* d_out, int out_size, void* d_ws, size_t ws_size,
                              hipStream_t stream) {
  const float* x_t = (const float*)d_in[0];
  const float* h_prev = (const float*)d_in[1];
  const float* adj = (const float*)d_in[2];
  const float* Wz = (const float*)d_in[3];
  const float* bz = (const float*)d_in[4];
  const float* Wr = (const float*)d_in[5];
  const float* br = (const float*)d_in[6];
  const float* Wh = (const float*)d_in[7];
  const float* bh = (const float*)d_in[8];
  const float* gamma = (const float*)d_in[9];
  const float* beta = (const float*)d_in[10];
  float* out = (float*)d_out;

  if (ws_size < (size_t)151363584) return;

  char* ws = (char*)d_ws;
  char* adjq = ws;                              // 16,777,216 B (i8, adj*2^18)
  char* gt0q = ws + 16777216;                   // 10,485,760 B (i8, *16)
  char* gt1q = ws + 27262976;                   // 10,485,760 B (i8, hop*2^10)
  u16* grows = (u16*)(ws + 37748736);           // 62,914,560 B
  u16* zbuf = (u16*)(ws + 100663296);           // 16,777,216 B
  u16* rbuf = (u16*)(ws + 117440512);           // 16,777,216 B
  u16* htb = (u16*)(ws + 134217728);            // 16,777,216 B
  u16* wzr = (u16*)(ws + 150994944);            // 245,760 B
  u16* whb = (u16*)(ws + 151240704);            // 122,880 B

  // descales: A=2^18, xh-B=2^4 -> hop1 true = acc*2^-22 ; hop-B=2^10 -> hop2 = acc*2^-28
  const float D22 = 1.f / 4194304.f, D28 = 1.f / 268435456.f, D12 = 1.f / 4096.f;

  dim3 blk(256);
  cvt_adj_i8<<<dim3(16384), blk, 0, stream>>>(adj, (u32*)adjq, 4194304);
  cvt_w3<<<dim3(180), blk, 0, stream>>>(Wz, Wr, Wh, wzr, whb);
  prep_kernel<<<dim3(64, 16), blk, 0, stream>>>(x_t, h_prev, gt0q, grows);
  // phase 1 diffusion (1D grid, XCD M-slab swizzle; 640 % 8 == 0)
  gemm_mix_i8<0, 1><<<dim3(640), dim3(512), 0, stream>>>(adjq, gt0q, gt1q,
                                                         grows + 160, D22, D12);
  gemm_mix_i8<0, 0><<<dim3(640), dim3(512), 0, stream>>>(adjq, gt1q, nullptr,
                                                         grows + 320, D28, 0.f);
  // z, r gates
  gemm_gate<1><<<dim3(512, 2), blk, 0, stream>>>(grows, wzr, zbuf, rbuf, bz, br);
  // cand: multiply h-features by r (both layouts)
  cand_kernel<<<dim3(64, 16), blk, 0, stream>>>(grows, gt0q, rbuf);
  // phase 2 diffusion (h-channels only; 512 % 8 == 0)
  gemm_mix_i8<1, 1><<<dim3(512), dim3(512), 0, stream>>>(adjq, gt0q, gt1q,
                                                         grows + 160, D22, D12);
  gemm_mix_i8<1, 0><<<dim3(512), dim3(512), 0, stream>>>(adjq, gt1q, nullptr,
                                                         grows + 320, D28, 0.f);
  // h_tilde
  gemm_gate<2><<<dim3(512, 1), blk, 0, stream>>>(grows, whb, htb, nullptr, bh, nullptr);
  final_kernel<<<dim3(16384), blk, 0, stream>>>(htb, zbuf, h_prev, gamma, beta, out);
}